// Round 1
// baseline (426.780 us; speedup 1.0000x reference)
//
#include <hip/hip_runtime.h>
#include <math.h>

#define NN 50000
#define NE 800000
#define IN_F 256
#define HF 256   // H*F
#define NH 8
#define NF 32
#define NEG_SLOPE 0.2f

// ---------------- GEMM: h = feat @ W  (fp32, 128x128 tile, 8x8 micro) ----------
#define BM 128
#define BN 128
#define BK 16

__global__ __launch_bounds__(256) void gemm_kernel(const float* __restrict__ A,
                                                   const float* __restrict__ B,
                                                   float* __restrict__ C, int M) {
    __shared__ float As[BK][BM];   // k-major
    __shared__ float Bs[BK][BN];
    const int bm = blockIdx.x * BM;
    const int bn = blockIdx.y * BN;
    const int tid = threadIdx.x;
    const int tx = tid & 15;   // col group (8 cols each)
    const int ty = tid >> 4;   // row group (8 rows each)

    float acc[8][8];
    #pragma unroll
    for (int i = 0; i < 8; ++i)
        #pragma unroll
        for (int j = 0; j < 8; ++j) acc[i][j] = 0.f;

    const int ra0 = tid >> 2;          // 0..63, A row (and +64)
    const int kc  = (tid & 3) * 4;     // k chunk within BK
    const int brow = tid >> 5;         // 0..7, B k-row (and +8)
    const int bcol = (tid & 31) * 4;   // B col chunk

    const int nk = IN_F / BK;
    for (int kt = 0; kt < nk; ++kt) {
        const int k0 = kt * BK;
        // stage A tile (k-major in LDS)
        #pragma unroll
        for (int rr = 0; rr < 2; ++rr) {
            int row = ra0 + rr * 64;
            int grow = bm + row;
            float4 av = make_float4(0.f, 0.f, 0.f, 0.f);
            if (grow < M) av = *(const float4*)&A[(size_t)grow * IN_F + k0 + kc];
            As[kc + 0][row] = av.x;
            As[kc + 1][row] = av.y;
            As[kc + 2][row] = av.z;
            As[kc + 3][row] = av.w;
        }
        // stage B tile
        #pragma unroll
        for (int rr = 0; rr < 2; ++rr) {
            int krow = brow + rr * 8;
            float4 bv = *(const float4*)&B[(size_t)(k0 + krow) * HF + bn + bcol];
            *(float4*)&Bs[krow][bcol] = bv;
        }
        __syncthreads();
        #pragma unroll
        for (int k = 0; k < BK; ++k) {
            float4 a0 = *(const float4*)&As[k][ty * 8];
            float4 a1 = *(const float4*)&As[k][ty * 8 + 4];
            float4 b0 = *(const float4*)&Bs[k][tx * 8];
            float4 b1 = *(const float4*)&Bs[k][tx * 8 + 4];
            float av[8] = {a0.x, a0.y, a0.z, a0.w, a1.x, a1.y, a1.z, a1.w};
            float bv[8] = {b0.x, b0.y, b0.z, b0.w, b1.x, b1.y, b1.z, b1.w};
            #pragma unroll
            for (int i = 0; i < 8; ++i)
                #pragma unroll
                for (int j = 0; j < 8; ++j)
                    acc[i][j] = fmaf(av[i], bv[j], acc[i][j]);
        }
        __syncthreads();
    }
    // epilogue
    #pragma unroll
    for (int i = 0; i < 8; ++i) {
        int grow = bm + ty * 8 + i;
        if (grow < M) {
            float4 o0 = make_float4(acc[i][0], acc[i][1], acc[i][2], acc[i][3]);
            float4 o1 = make_float4(acc[i][4], acc[i][5], acc[i][6], acc[i][7]);
            *(float4*)&C[(size_t)grow * HF + bn + tx * 8] = o0;
            *(float4*)&C[(size_t)grow * HF + bn + tx * 8 + 4] = o1;
        }
    }
}

// ---------------- el/er per node: one wave per node ----------------
__global__ __launch_bounds__(256) void elr_kernel(const float* __restrict__ h,
                                                  const float* __restrict__ al,
                                                  const float* __restrict__ ar,
                                                  float* __restrict__ el,
                                                  float* __restrict__ er) {
    int node = blockIdx.x * 4 + (threadIdx.x >> 6);
    if (node >= NN) return;
    int lane = threadIdx.x & 63;
    float4 hv  = *(const float4*)&h[(size_t)node * HF + lane * 4];
    float4 alv = *(const float4*)&al[lane * 4];
    float4 arv = *(const float4*)&ar[lane * 4];
    float pl = hv.x * alv.x + hv.y * alv.y + hv.z * alv.z + hv.w * alv.w;
    float pr = hv.x * arv.x + hv.y * arv.y + hv.z * arv.z + hv.w * arv.w;
    #pragma unroll
    for (int off = 1; off < 8; off <<= 1) {
        pl += __shfl_xor(pl, off);
        pr += __shfl_xor(pr, off);
    }
    if ((lane & 7) == 0) {
        int hd = lane >> 3;
        el[node * NH + hd] = pl;
        er[node * NH + hd] = pr;
    }
}

// ---------------- CSR build ----------------
__global__ void deg_kernel(const int* __restrict__ dst, int* __restrict__ deg) {
    int e = blockIdx.x * 256 + threadIdx.x;
    if (e < NE) atomicAdd(&deg[dst[e]], 1);
}

__global__ __launch_bounds__(1024) void scan_kernel(const int* __restrict__ deg,
                                                    int* __restrict__ row_ptr,
                                                    int* __restrict__ cursor) {
    __shared__ int sdata[1024];
    int tid = threadIdx.x;
    if (tid == 0) row_ptr[0] = 0;
    int carry = 0;
    for (int base = 0; base < NN; base += 1024) {
        int i = base + tid;
        int v = (i < NN) ? deg[i] : 0;
        sdata[tid] = v;
        __syncthreads();
        #pragma unroll
        for (int off = 1; off < 1024; off <<= 1) {
            int y = (tid >= off) ? sdata[tid - off] : 0;
            __syncthreads();
            sdata[tid] += y;
            __syncthreads();
        }
        int incl = sdata[tid];
        if (i < NN) {
            row_ptr[i + 1] = carry + incl;
            cursor[i] = carry + incl - v;   // exclusive
        }
        carry += sdata[1023];
        __syncthreads();
    }
}

__global__ void fill_kernel(const int* __restrict__ src, const int* __restrict__ dst,
                            int* __restrict__ cursor, int* __restrict__ csr_src) {
    int e = blockIdx.x * 256 + threadIdx.x;
    if (e < NE) {
        int d = dst[e];
        int pos = atomicAdd(&cursor[d], 1);
        csr_src[pos] = src[e];
    }
}

// ---------------- per-node softmax + aggregate: one wave per node ----------------
__global__ __launch_bounds__(256) void agg_kernel(const float* __restrict__ h,
                                                  const float* __restrict__ el,
                                                  const float* __restrict__ er,
                                                  const int* __restrict__ row_ptr,
                                                  const int* __restrict__ csr_src,
                                                  const float* __restrict__ bias,
                                                  float* __restrict__ out) {
    int node = blockIdx.x * 4 + (threadIdx.x >> 6);
    if (node >= NN) return;
    int lane = threadIdx.x & 63;
    int beg = row_ptr[node];
    int end = row_ptr[node + 1];

    // er row for this node (all lanes hold all 8)
    float er_n[8];
    {
        float4 e0 = *(const float4*)&er[(size_t)node * NH];
        float4 e1 = *(const float4*)&er[(size_t)node * NH + 4];
        er_n[0] = e0.x; er_n[1] = e0.y; er_n[2] = e0.z; er_n[3] = e0.w;
        er_n[4] = e1.x; er_n[5] = e1.y; er_n[6] = e1.z; er_n[7] = e1.w;
    }

    // pass A: per-head max
    float m[8];
    #pragma unroll
    for (int hd = 0; hd < 8; ++hd) m[hd] = -INFINITY;
    for (int i = beg + lane; i < end; i += 64) {
        int s = csr_src[i];
        float4 l0 = *(const float4*)&el[(size_t)s * NH];
        float4 l1 = *(const float4*)&el[(size_t)s * NH + 4];
        float elv[8] = {l0.x, l0.y, l0.z, l0.w, l1.x, l1.y, l1.z, l1.w};
        #pragma unroll
        for (int hd = 0; hd < 8; ++hd) {
            float e = elv[hd] + er_n[hd];
            e = e > 0.f ? e : NEG_SLOPE * e;
            m[hd] = fmaxf(m[hd], e);
        }
    }
    #pragma unroll
    for (int hd = 0; hd < 8; ++hd) {
        #pragma unroll
        for (int off = 32; off >= 1; off >>= 1)
            m[hd] = fmaxf(m[hd], __shfl_xor(m[hd], off));
    }

    // pass B: per-head sum of exp
    float ssum[8];
    #pragma unroll
    for (int hd = 0; hd < 8; ++hd) ssum[hd] = 0.f;
    for (int i = beg + lane; i < end; i += 64) {
        int s = csr_src[i];
        float4 l0 = *(const float4*)&el[(size_t)s * NH];
        float4 l1 = *(const float4*)&el[(size_t)s * NH + 4];
        float elv[8] = {l0.x, l0.y, l0.z, l0.w, l1.x, l1.y, l1.z, l1.w};
        #pragma unroll
        for (int hd = 0; hd < 8; ++hd) {
            float e = elv[hd] + er_n[hd];
            e = e > 0.f ? e : NEG_SLOPE * e;
            ssum[hd] += __expf(e - m[hd]);
        }
    }
    #pragma unroll
    for (int hd = 0; hd < 8; ++hd) {
        #pragma unroll
        for (int off = 32; off >= 1; off >>= 1)
            ssum[hd] += __shfl_xor(ssum[hd], off);
    }

    // select per-lane head-scalars without dynamic register indexing
    int hd_mine = lane >> 3;
    float m_mine = m[0], s_mine = ssum[0], er_mine = er_n[0];
    #pragma unroll
    for (int t = 1; t < 8; ++t) {
        if (hd_mine == t) { m_mine = m[t]; s_mine = ssum[t]; er_mine = er_n[t]; }
    }
    float inv_s = (s_mine > 0.f) ? 1.f / s_mine : 0.f;

    // pass C: accumulate weighted h[src]
    float4 acc = *(const float4*)&bias[lane * 4];
    for (int i = beg; i < end; ++i) {
        int s = csr_src[i];
        float e = el[(size_t)s * NH + hd_mine] + er_mine;
        e = e > 0.f ? e : NEG_SLOPE * e;
        float a = __expf(e - m_mine) * inv_s;
        float4 hv = *(const float4*)&h[(size_t)s * HF + lane * 4];
        acc.x = fmaf(hv.x, a, acc.x);
        acc.y = fmaf(hv.y, a, acc.y);
        acc.z = fmaf(hv.z, a, acc.z);
        acc.w = fmaf(hv.w, a, acc.w);
    }
    *(float4*)&out[(size_t)node * HF + lane * 4] = acc;
}

extern "C" void kernel_launch(void* const* d_in, const int* in_sizes, int n_in,
                              void* d_out, int out_size, void* d_ws, size_t ws_size,
                              hipStream_t stream) {
    const float* feat = (const float*)d_in[0];
    const float* W    = (const float*)d_in[1];
    const float* al   = (const float*)d_in[2];
    const float* ar   = (const float*)d_in[3];
    const float* bias = (const float*)d_in[4];
    const int*   src  = (const int*)d_in[5];
    const int*   dst  = (const int*)d_in[6];
    float* out = (float*)d_out;

    char* ws = (char*)d_ws;
    size_t off = 0;
    float* h = (float*)(ws + off);        off += (size_t)NN * HF * 4;        // 51.2 MB
    float* el = (float*)(ws + off);       off += (size_t)NN * NH * 4;        // 1.6 MB
    float* er = (float*)(ws + off);       off += (size_t)NN * NH * 4;        // 1.6 MB
    int* deg = (int*)(ws + off);          off += (size_t)NN * 4;
    int* row_ptr = (int*)(ws + off);      off += (size_t)(NN + 1) * 4 + 60;  // pad/align
    off &= ~(size_t)63;
    int* cursor = (int*)(ws + off);       off += (size_t)NN * 4;
    int* csr_src = (int*)(ws + off);      off += (size_t)NE * 4;

    hipMemsetAsync(deg, 0, (size_t)NN * 4, stream);

    gemm_kernel<<<dim3((NN + BM - 1) / BM, HF / BN), 256, 0, stream>>>(feat, W, h, NN);
    elr_kernel<<<NN / 4, 256, 0, stream>>>(h, al, ar, el, er);
    deg_kernel<<<NE / 256, 256, 0, stream>>>(dst, deg);
    scan_kernel<<<1, 1024, 0, stream>>>(deg, row_ptr, cursor);
    fill_kernel<<<NE / 256, 256, 0, stream>>>(src, dst, cursor, csr_src);
    agg_kernel<<<NN / 4, 256, 0, stream>>>(h, el, er, row_ptr, csr_src, bias, out);
}

// Round 2
// 317.264 us; speedup vs baseline: 1.3452x; 1.3452x over previous
//
#include <hip/hip_runtime.h>
#include <math.h>

#define NN 50000
#define NE 800000
#define IN_F 256
#define HF 256   // H*F
#define NH 8
#define NEG_SLOPE 0.2f

typedef short bf16x8 __attribute__((ext_vector_type(8)));
typedef float f32x16 __attribute__((ext_vector_type(16)));

__device__ __forceinline__ unsigned short f2bf(float x) {
    unsigned u = __float_as_uint(x);
    u += 0x7FFF + ((u >> 16) & 1);          // round-to-nearest-even
    return (unsigned short)(u >> 16);
}
__device__ __forceinline__ float bf2f(unsigned short b) {
    return __uint_as_float(((unsigned)b) << 16);
}

// ---- W -> transposed, K-step-blocked, chunk-swizzled bf16 hi/lo ------------
// Layout: Wb[kt][n][slot*8+j] holds W[kt*32 + c*8 + j][n], slot = c ^ (n&3).
__global__ __launch_bounds__(256) void wconv_kernel(const float* __restrict__ W,
                                                    unsigned short* __restrict__ Wb_hi,
                                                    unsigned short* __restrict__ Wb_lo) {
    int e = blockIdx.x * 256 + threadIdx.x;   // 65536 = 256k x 256n
    int k = e >> 8, n = e & 255;
    float x = W[e];                            // e == k*256 + n, coalesced
    unsigned short hi = f2bf(x);
    unsigned short lo = f2bf(x - bf2f(hi));
    int kt = k >> 5, kk = k & 31, c = kk >> 3, j = kk & 7;
    int slot = c ^ (n & 3);
    size_t idx = ((size_t)(kt * 256 + n)) * 32 + slot * 8 + j;
    Wb_hi[idx] = hi;
    Wb_lo[idx] = lo;
}

// ---- GEMM: h_bf16 = bf16(feat @ W), 3-term bf16-split MFMA -----------------
// BM=64, BN=256(all), BK=32, 4 waves each 64x64, 32x32x16 bf16 MFMA.
__global__ __launch_bounds__(256) void gemm_kernel(const float* __restrict__ feat,
                                                   const unsigned short* __restrict__ Wb_hi,
                                                   const unsigned short* __restrict__ Wb_lo,
                                                   unsigned short* __restrict__ h, int M) {
    __shared__ __align__(16) unsigned short As_hi[64][32];
    __shared__ __align__(16) unsigned short As_lo[64][32];
    __shared__ __align__(16) unsigned short Bs_hi[256][32];
    __shared__ __align__(16) unsigned short Bs_lo[256][32];

    const int tid = threadIdx.x;
    const int lane = tid & 63;
    const int wid = tid >> 6;
    const int bm = blockIdx.x * 64;

    f32x16 acc[2][2];
    #pragma unroll
    for (int mi = 0; mi < 2; ++mi)
        #pragma unroll
        for (int ni = 0; ni < 2; ++ni)
            #pragma unroll
            for (int r = 0; r < 16; ++r) acc[mi][ni][r] = 0.f;

    const int arow = tid >> 2;          // 0..63
    const int achk = tid & 3;           // 16B chunk (8 floats)
    const int aslot = achk ^ (arow & 3);
    const int grow = bm + arow;
    const float* aptr = feat + (size_t)grow * IN_F + achk * 8;

    for (int kt = 0; kt < 8; ++kt) {
        __syncthreads();
        // ---- stage A (fp32 load -> hi/lo bf16 -> swizzled ds_write) ----
        float4 f0 = make_float4(0.f, 0.f, 0.f, 0.f), f1 = f0;
        if (grow < M) {
            f0 = *(const float4*)(aptr + kt * 32);
            f1 = *(const float4*)(aptr + kt * 32 + 4);
        }
        float xs[8] = {f0.x, f0.y, f0.z, f0.w, f1.x, f1.y, f1.z, f1.w};
        unsigned hi2[4], lo2[4];
        #pragma unroll
        for (int p = 0; p < 4; ++p) {
            unsigned short h0 = f2bf(xs[2 * p]), h1 = f2bf(xs[2 * p + 1]);
            unsigned short l0 = f2bf(xs[2 * p] - bf2f(h0));
            unsigned short l1 = f2bf(xs[2 * p + 1] - bf2f(h1));
            hi2[p] = (unsigned)h0 | ((unsigned)h1 << 16);
            lo2[p] = (unsigned)l0 | ((unsigned)l1 << 16);
        }
        *(int4*)&As_hi[arow][aslot * 8] = make_int4(hi2[0], hi2[1], hi2[2], hi2[3]);
        *(int4*)&As_lo[arow][aslot * 8] = make_int4(lo2[0], lo2[1], lo2[2], lo2[3]);
        // ---- stage B (pre-swizzled in memory -> linear copy) ----
        {
            const int4* gh = (const int4*)(Wb_hi + (size_t)kt * 8192) + tid * 4;
            const int4* gl = (const int4*)(Wb_lo + (size_t)kt * 8192) + tid * 4;
            int4* dh = (int4*)&Bs_hi[tid][0];
            int4* dl = (int4*)&Bs_lo[tid][0];
            #pragma unroll
            for (int q = 0; q < 4; ++q) { dh[q] = gh[q]; dl[q] = gl[q]; }
        }
        __syncthreads();
        // ---- MFMA ----
        #pragma unroll
        for (int ksc = 0; ksc < 2; ++ksc) {
            bf16x8 ah[2], av[2], bh[2], bv[2];
            const int kc = ksc * 2 + (lane >> 5);
            #pragma unroll
            for (int mi = 0; mi < 2; ++mi) {
                int r = mi * 32 + (lane & 31);
                int slot = kc ^ (r & 3);
                ah[mi] = *(const bf16x8*)&As_hi[r][slot * 8];
                av[mi] = *(const bf16x8*)&As_lo[r][slot * 8];
            }
            #pragma unroll
            for (int ni = 0; ni < 2; ++ni) {
                int n = wid * 64 + ni * 32 + (lane & 31);
                int slot = kc ^ (n & 3);
                bh[ni] = *(const bf16x8*)&Bs_hi[n][slot * 8];
                bv[ni] = *(const bf16x8*)&Bs_lo[n][slot * 8];
            }
            #pragma unroll
            for (int mi = 0; mi < 2; ++mi)
                #pragma unroll
                for (int ni = 0; ni < 2; ++ni) {
                    acc[mi][ni] = __builtin_amdgcn_mfma_f32_32x32x16_bf16(ah[mi], bh[ni], acc[mi][ni], 0, 0, 0);
                    acc[mi][ni] = __builtin_amdgcn_mfma_f32_32x32x16_bf16(ah[mi], bv[ni], acc[mi][ni], 0, 0, 0);
                    acc[mi][ni] = __builtin_amdgcn_mfma_f32_32x32x16_bf16(av[mi], bh[ni], acc[mi][ni], 0, 0, 0);
                }
        }
    }
    // ---- epilogue: bf16 store ----
    #pragma unroll
    for (int mi = 0; mi < 2; ++mi)
        #pragma unroll
        for (int ni = 0; ni < 2; ++ni)
            #pragma unroll
            for (int r = 0; r < 16; ++r) {
                int row = mi * 32 + (r & 3) + 8 * (r >> 2) + 4 * (lane >> 5);
                int col = wid * 64 + ni * 32 + (lane & 31);
                int gr = bm + row;
                if (gr < M) h[(size_t)gr * HF + col] = f2bf(acc[mi][ni][r]);
            }
}

// ---- el/er per node: one wave per node -------------------------------------
__global__ __launch_bounds__(256) void elr_kernel(const unsigned short* __restrict__ h,
                                                  const float* __restrict__ al,
                                                  const float* __restrict__ ar,
                                                  float* __restrict__ el,
                                                  float* __restrict__ er) {
    int node = blockIdx.x * 4 + (threadIdx.x >> 6);
    if (node >= NN) return;
    int lane = threadIdx.x & 63;
    short4 hv = *(const short4*)&h[(size_t)node * HF + lane * 4];
    float h0 = bf2f((unsigned short)hv.x), h1 = bf2f((unsigned short)hv.y);
    float h2 = bf2f((unsigned short)hv.z), h3 = bf2f((unsigned short)hv.w);
    float4 alv = *(const float4*)&al[lane * 4];
    float4 arv = *(const float4*)&ar[lane * 4];
    float pl = h0 * alv.x + h1 * alv.y + h2 * alv.z + h3 * alv.w;
    float pr = h0 * arv.x + h1 * arv.y + h2 * arv.z + h3 * arv.w;
    #pragma unroll
    for (int off = 1; off < 8; off <<= 1) {
        pl += __shfl_xor(pl, off);
        pr += __shfl_xor(pr, off);
    }
    if ((lane & 7) == 0) {
        el[node * NH + (lane >> 3)] = pl;
        er[node * NH + (lane >> 3)] = pr;
    }
}

// ---- CSR build -------------------------------------------------------------
__global__ void deg_kernel(const int* __restrict__ dst, int* __restrict__ deg) {
    int e = blockIdx.x * 256 + threadIdx.x;
    if (e < NE) atomicAdd(&deg[dst[e]], 1);
}

__global__ __launch_bounds__(1024) void scan_kernel(const int* __restrict__ deg,
                                                    int* __restrict__ row_ptr,
                                                    int* __restrict__ cursor) {
    __shared__ int wsum[16];
    int tid = threadIdx.x, lane = tid & 63, wid = tid >> 6;
    int carry = 0;
    if (tid == 0) row_ptr[0] = 0;
    for (int base = 0; base < NN; base += 1024) {
        int i = base + tid;
        int v = (i < NN) ? deg[i] : 0;
        int x = v;
        #pragma unroll
        for (int off = 1; off < 64; off <<= 1) {
            int y = __shfl_up(x, off);
            if (lane >= off) x += y;
        }
        if (lane == 63) wsum[wid] = x;
        __syncthreads();
        int wadd = 0, tot = 0;
        #pragma unroll
        for (int w = 0; w < 16; ++w) {
            int s = wsum[w];
            tot += s;
            if (w < wid) wadd += s;
        }
        if (i < NN) {
            int incl = carry + wadd + x;
            row_ptr[i + 1] = incl;
            cursor[i] = incl - v;
        }
        carry += tot;
        __syncthreads();
    }
}

__global__ void fill_kernel(const int* __restrict__ src, const int* __restrict__ dst,
                            int* __restrict__ cursor, int* __restrict__ csr_src) {
    int e = blockIdx.x * 256 + threadIdx.x;
    if (e < NE) {
        int d = dst[e];
        int pos = atomicAdd(&cursor[d], 1);
        csr_src[pos] = src[e];
    }
}

// ---- per-node softmax + aggregate: one wave per node -----------------------
__global__ __launch_bounds__(256) void agg_kernel(const unsigned short* __restrict__ h,
                                                  const float* __restrict__ el,
                                                  const float* __restrict__ er,
                                                  const int* __restrict__ row_ptr,
                                                  const int* __restrict__ csr_src,
                                                  const float* __restrict__ bias,
                                                  float* __restrict__ out) {
    int node = blockIdx.x * 4 + (threadIdx.x >> 6);
    if (node >= NN) return;
    int lane = threadIdx.x & 63;
    int beg = row_ptr[node];
    int end = row_ptr[node + 1];

    float er_n[8];
    {
        float4 e0 = *(const float4*)&er[(size_t)node * NH];
        float4 e1 = *(const float4*)&er[(size_t)node * NH + 4];
        er_n[0] = e0.x; er_n[1] = e0.y; er_n[2] = e0.z; er_n[3] = e0.w;
        er_n[4] = e1.x; er_n[5] = e1.y; er_n[6] = e1.z; er_n[7] = e1.w;
    }

    // pass A: per-head max
    float m[8];
    #pragma unroll
    for (int hd = 0; hd < 8; ++hd) m[hd] = -INFINITY;
    for (int i = beg + lane; i < end; i += 64) {
        int s = csr_src[i];
        float4 l0 = *(const float4*)&el[(size_t)s * NH];
        float4 l1 = *(const float4*)&el[(size_t)s * NH + 4];
        float elv[8] = {l0.x, l0.y, l0.z, l0.w, l1.x, l1.y, l1.z, l1.w};
        #pragma unroll
        for (int hd = 0; hd < 8; ++hd) {
            float e = elv[hd] + er_n[hd];
            e = e > 0.f ? e : NEG_SLOPE * e;
            m[hd] = fmaxf(m[hd], e);
        }
    }
    #pragma unroll
    for (int hd = 0; hd < 8; ++hd) {
        #pragma unroll
        for (int off = 32; off >= 1; off >>= 1)
            m[hd] = fmaxf(m[hd], __shfl_xor(m[hd], off));
    }

    // pass B: per-head sum of exp
    float ssum[8];
    #pragma unroll
    for (int hd = 0; hd < 8; ++hd) ssum[hd] = 0.f;
    for (int i = beg + lane; i < end; i += 64) {
        int s = csr_src[i];
        float4 l0 = *(const float4*)&el[(size_t)s * NH];
        float4 l1 = *(const float4*)&el[(size_t)s * NH + 4];
        float elv[8] = {l0.x, l0.y, l0.z, l0.w, l1.x, l1.y, l1.z, l1.w};
        #pragma unroll
        for (int hd = 0; hd < 8; ++hd) {
            float e = elv[hd] + er_n[hd];
            e = e > 0.f ? e : NEG_SLOPE * e;
            ssum[hd] += __expf(e - m[hd]);
        }
    }
    #pragma unroll
    for (int hd = 0; hd < 8; ++hd) {
        #pragma unroll
        for (int off = 32; off >= 1; off >>= 1)
            ssum[hd] += __shfl_xor(ssum[hd], off);
    }

    int hd_mine = lane >> 3;
    float m_mine = m[0], s_mine = ssum[0], er_mine = er_n[0];
    #pragma unroll
    for (int t = 1; t < 8; ++t) {
        if (hd_mine == t) { m_mine = m[t]; s_mine = ssum[t]; er_mine = er_n[t]; }
    }
    float inv_s = (s_mine > 0.f) ? 1.f / s_mine : 0.f;

    // pass C: accumulate weighted h[src] (bf16)
    float4 acc = *(const float4*)&bias[lane * 4];
    for (int i = beg; i < end; ++i) {
        int s = csr_src[i];
        float e = el[(size_t)s * NH + hd_mine] + er_mine;
        e = e > 0.f ? e : NEG_SLOPE * e;
        float a = __expf(e - m_mine) * inv_s;
        short4 hv = *(const short4*)&h[(size_t)s * HF + lane * 4];
        acc.x = fmaf(bf2f((unsigned short)hv.x), a, acc.x);
        acc.y = fmaf(bf2f((unsigned short)hv.y), a, acc.y);
        acc.z = fmaf(bf2f((unsigned short)hv.z), a, acc.z);
        acc.w = fmaf(bf2f((unsigned short)hv.w), a, acc.w);
    }
    *(float4*)&out[(size_t)node * HF + lane * 4] = acc;
}

extern "C" void kernel_launch(void* const* d_in, const int* in_sizes, int n_in,
                              void* d_out, int out_size, void* d_ws, size_t ws_size,
                              hipStream_t stream) {
    const float* feat = (const float*)d_in[0];
    const float* W    = (const float*)d_in[1];
    const float* al   = (const float*)d_in[2];
    const float* ar   = (const float*)d_in[3];
    const float* bias = (const float*)d_in[4];
    const int*   src  = (const int*)d_in[5];
    const int*   dst  = (const int*)d_in[6];
    float* out = (float*)d_out;

    char* ws = (char*)d_ws;
    size_t off = 0;
    unsigned short* h = (unsigned short*)(ws + off); off += (size_t)NN * HF * 2;   // 25.6 MB
    float* el = (float*)(ws + off);                  off += (size_t)NN * NH * 4;
    float* er = (float*)(ws + off);                  off += (size_t)NN * NH * 4;
    int* deg = (int*)(ws + off);                     off += (size_t)NN * 4;
    int* row_ptr = (int*)(ws + off);                 off += (size_t)(NN + 1) * 4 + 60;
    off &= ~(size_t)63;
    int* cursor = (int*)(ws + off);                  off += (size_t)NN * 4;
    int* csr_src = (int*)(ws + off);                 off += (size_t)NE * 4;
    unsigned short* Wb_hi = (unsigned short*)(ws + off); off += (size_t)IN_F * HF * 2;
    unsigned short* Wb_lo = (unsigned short*)(ws + off); off += (size_t)IN_F * HF * 2;

    hipMemsetAsync(deg, 0, (size_t)NN * 4, stream);

    wconv_kernel<<<256, 256, 0, stream>>>(W, Wb_hi, Wb_lo);
    gemm_kernel<<<(NN + 63) / 64, 256, 0, stream>>>(feat, Wb_hi, Wb_lo, h, NN);
    deg_kernel<<<NE / 256, 256, 0, stream>>>(dst, deg);
    scan_kernel<<<1, 1024, 0, stream>>>(deg, row_ptr, cursor);
    fill_kernel<<<NE / 256, 256, 0, stream>>>(src, dst, cursor, csr_src);
    elr_kernel<<<NN / 4, 256, 0, stream>>>(h, al, ar, el, er);
    agg_kernel<<<NN / 4, 256, 0, stream>>>(h, el, er, row_ptr, csr_src, bias, out);
}

// Round 3
// 227.654 us; speedup vs baseline: 1.8747x; 1.3936x over previous
//
#include <hip/hip_runtime.h>
#include <math.h>

#define NN 50000
#define NE 800000
#define IN_F 256
#define HF 256   // H*F
#define NH 8
#define NEG_SLOPE 0.2f

#define DEG_PAD 57344   // 7 * 8192, scan processes 8192/iter unguarded

typedef short bf16x8 __attribute__((ext_vector_type(8)));
typedef float f32x16 __attribute__((ext_vector_type(16)));

__device__ __forceinline__ unsigned short f2bf(float x) {
    unsigned u = __float_as_uint(x);
    u += 0x7FFF + ((u >> 16) & 1);          // round-to-nearest-even
    return (unsigned short)(u >> 16);
}
__device__ __forceinline__ float bf2f(unsigned short b) {
    return __uint_as_float(((unsigned)b) << 16);
}

// ---- W -> transposed, K-step-blocked, chunk-swizzled bf16 hi/lo ------------
__global__ __launch_bounds__(256) void wconv_kernel(const float* __restrict__ W,
                                                    unsigned short* __restrict__ Wb_hi,
                                                    unsigned short* __restrict__ Wb_lo) {
    int e = blockIdx.x * 256 + threadIdx.x;
    int k = e >> 8, n = e & 255;
    float x = W[e];
    unsigned short hi = f2bf(x);
    unsigned short lo = f2bf(x - bf2f(hi));
    int kt = k >> 5, kk = k & 31, c = kk >> 3, j = kk & 7;
    int slot = c ^ (n & 3);
    size_t idx = ((size_t)(kt * 256 + n)) * 32 + slot * 8 + j;
    Wb_hi[idx] = hi;
    Wb_lo[idx] = lo;
}

// ---- GEMM: h_bf16 = bf16(feat @ W), 3-term bf16-split MFMA -----------------
__global__ __launch_bounds__(256) void gemm_kernel(const float* __restrict__ feat,
                                                   const unsigned short* __restrict__ Wb_hi,
                                                   const unsigned short* __restrict__ Wb_lo,
                                                   unsigned short* __restrict__ h, int M) {
    __shared__ __align__(16) unsigned short As_hi[64][32];
    __shared__ __align__(16) unsigned short As_lo[64][32];
    __shared__ __align__(16) unsigned short Bs_hi[256][32];
    __shared__ __align__(16) unsigned short Bs_lo[256][32];

    const int tid = threadIdx.x;
    const int lane = tid & 63;
    const int wid = tid >> 6;
    const int bm = blockIdx.x * 64;

    f32x16 acc[2][2];
    #pragma unroll
    for (int mi = 0; mi < 2; ++mi)
        #pragma unroll
        for (int ni = 0; ni < 2; ++ni)
            #pragma unroll
            for (int r = 0; r < 16; ++r) acc[mi][ni][r] = 0.f;

    const int arow = tid >> 2;
    const int achk = tid & 3;
    const int aslot = achk ^ (arow & 3);
    const int grow = bm + arow;
    const float* aptr = feat + (size_t)grow * IN_F + achk * 8;

    for (int kt = 0; kt < 8; ++kt) {
        __syncthreads();
        float4 f0 = make_float4(0.f, 0.f, 0.f, 0.f), f1 = f0;
        if (grow < M) {
            f0 = *(const float4*)(aptr + kt * 32);
            f1 = *(const float4*)(aptr + kt * 32 + 4);
        }
        float xs[8] = {f0.x, f0.y, f0.z, f0.w, f1.x, f1.y, f1.z, f1.w};
        unsigned hi2[4], lo2[4];
        #pragma unroll
        for (int p = 0; p < 4; ++p) {
            unsigned short h0 = f2bf(xs[2 * p]), h1 = f2bf(xs[2 * p + 1]);
            unsigned short l0 = f2bf(xs[2 * p] - bf2f(h0));
            unsigned short l1 = f2bf(xs[2 * p + 1] - bf2f(h1));
            hi2[p] = (unsigned)h0 | ((unsigned)h1 << 16);
            lo2[p] = (unsigned)l0 | ((unsigned)l1 << 16);
        }
        *(int4*)&As_hi[arow][aslot * 8] = make_int4(hi2[0], hi2[1], hi2[2], hi2[3]);
        *(int4*)&As_lo[arow][aslot * 8] = make_int4(lo2[0], lo2[1], lo2[2], lo2[3]);
        {
            const int4* gh = (const int4*)(Wb_hi + (size_t)kt * 8192) + tid * 4;
            const int4* gl = (const int4*)(Wb_lo + (size_t)kt * 8192) + tid * 4;
            int4* dh = (int4*)&Bs_hi[tid][0];
            int4* dl = (int4*)&Bs_lo[tid][0];
            #pragma unroll
            for (int q = 0; q < 4; ++q) { dh[q] = gh[q]; dl[q] = gl[q]; }
        }
        __syncthreads();
        #pragma unroll
        for (int ksc = 0; ksc < 2; ++ksc) {
            bf16x8 ah[2], av[2], bh[2], bv[2];
            const int kc = ksc * 2 + (lane >> 5);
            #pragma unroll
            for (int mi = 0; mi < 2; ++mi) {
                int r = mi * 32 + (lane & 31);
                int slot = kc ^ (r & 3);
                ah[mi] = *(const bf16x8*)&As_hi[r][slot * 8];
                av[mi] = *(const bf16x8*)&As_lo[r][slot * 8];
            }
            #pragma unroll
            for (int ni = 0; ni < 2; ++ni) {
                int n = wid * 64 + ni * 32 + (lane & 31);
                int slot = kc ^ (n & 3);
                bh[ni] = *(const bf16x8*)&Bs_hi[n][slot * 8];
                bv[ni] = *(const bf16x8*)&Bs_lo[n][slot * 8];
            }
            #pragma unroll
            for (int mi = 0; mi < 2; ++mi)
                #pragma unroll
                for (int ni = 0; ni < 2; ++ni) {
                    acc[mi][ni] = __builtin_amdgcn_mfma_f32_32x32x16_bf16(ah[mi], bh[ni], acc[mi][ni], 0, 0, 0);
                    acc[mi][ni] = __builtin_amdgcn_mfma_f32_32x32x16_bf16(ah[mi], bv[ni], acc[mi][ni], 0, 0, 0);
                    acc[mi][ni] = __builtin_amdgcn_mfma_f32_32x32x16_bf16(av[mi], bh[ni], acc[mi][ni], 0, 0, 0);
                }
        }
    }
    #pragma unroll
    for (int mi = 0; mi < 2; ++mi)
        #pragma unroll
        for (int ni = 0; ni < 2; ++ni)
            #pragma unroll
            for (int r = 0; r < 16; ++r) {
                int row = mi * 32 + (r & 3) + 8 * (r >> 2) + 4 * (lane >> 5);
                int col = wid * 64 + ni * 32 + (lane & 31);
                int gr = bm + row;
                if (gr < M) h[(size_t)gr * HF + col] = f2bf(acc[mi][ni][r]);
            }
}

// ---- el/er per node --------------------------------------------------------
__global__ __launch_bounds__(256) void elr_kernel(const unsigned short* __restrict__ h,
                                                  const float* __restrict__ al,
                                                  const float* __restrict__ ar,
                                                  float* __restrict__ el,
                                                  float* __restrict__ er) {
    int node = blockIdx.x * 4 + (threadIdx.x >> 6);
    if (node >= NN) return;
    int lane = threadIdx.x & 63;
    short4 hv = *(const short4*)&h[(size_t)node * HF + lane * 4];
    float h0 = bf2f((unsigned short)hv.x), h1 = bf2f((unsigned short)hv.y);
    float h2 = bf2f((unsigned short)hv.z), h3 = bf2f((unsigned short)hv.w);
    float4 alv = *(const float4*)&al[lane * 4];
    float4 arv = *(const float4*)&ar[lane * 4];
    float pl = h0 * alv.x + h1 * alv.y + h2 * alv.z + h3 * alv.w;
    float pr = h0 * arv.x + h1 * arv.y + h2 * arv.z + h3 * arv.w;
    #pragma unroll
    for (int off = 1; off < 8; off <<= 1) {
        pl += __shfl_xor(pl, off);
        pr += __shfl_xor(pr, off);
    }
    if ((lane & 7) == 0) {
        el[node * NH + (lane >> 3)] = pl;
        er[node * NH + (lane >> 3)] = pr;
    }
}

// ---- CSR build -------------------------------------------------------------
__global__ void deg_kernel(const int* __restrict__ dst, int* __restrict__ deg) {
    int e = blockIdx.x * 256 + threadIdx.x;
    if (e < NE) atomicAdd(&deg[dst[e]], 1);
}

// 8 elements/thread, 7 outer iterations over padded (zeroed) deg
__global__ __launch_bounds__(1024) void scan_kernel(const int* __restrict__ deg,
                                                    int* __restrict__ row_ptr,
                                                    int* __restrict__ cursor) {
    __shared__ int wsum[16];
    int tid = threadIdx.x, lane = tid & 63, wid = tid >> 6;
    int carry = 0;
    if (tid == 0) row_ptr[0] = 0;
    for (int base = 0; base < DEG_PAD; base += 8192) {
        int i0 = base + tid * 8;
        int4 a = *(const int4*)&deg[i0];
        int4 b = *(const int4*)&deg[i0 + 4];
        int v[8] = {a.x, a.y, a.z, a.w, b.x, b.y, b.z, b.w};
        int s8 = 0;
        #pragma unroll
        for (int j = 0; j < 8; ++j) s8 += v[j];
        int x = s8;
        #pragma unroll
        for (int off = 1; off < 64; off <<= 1) {
            int y = __shfl_up(x, off);
            if (lane >= off) x += y;
        }
        if (lane == 63) wsum[wid] = x;
        __syncthreads();
        int wadd = 0, tot = 0;
        #pragma unroll
        for (int w = 0; w < 16; ++w) {
            int s = wsum[w];
            tot += s;
            if (w < wid) wadd += s;
        }
        int r = carry + wadd + (x - s8);   // exclusive start of this thread
        #pragma unroll
        for (int j = 0; j < 8; ++j) {
            int i = i0 + j;
            if (i < NN) { cursor[i] = r; row_ptr[i + 1] = r + v[j]; }
            r += v[j];
        }
        carry += tot;
        __syncthreads();
    }
}

// fill CSR and per-edge exp(leaky(el+er)) in CSR order (no max: logits ~N(0,0.6))
__global__ void fill_kernel(const int* __restrict__ src, const int* __restrict__ dst,
                            int* __restrict__ cursor, int* __restrict__ csr_src,
                            const float* __restrict__ el, const float* __restrict__ er,
                            float* __restrict__ pexp) {
    int e = blockIdx.x * 256 + threadIdx.x;
    if (e >= NE) return;
    int d = dst[e], s = src[e];
    int pos = atomicAdd(&cursor[d], 1);
    csr_src[pos] = s;
    float4 l0 = *(const float4*)&el[(size_t)s * NH];
    float4 l1 = *(const float4*)&el[(size_t)s * NH + 4];
    float4 r0 = *(const float4*)&er[(size_t)d * NH];
    float4 r1 = *(const float4*)&er[(size_t)d * NH + 4];
    float xv[8] = {l0.x + r0.x, l0.y + r0.y, l0.z + r0.z, l0.w + r0.w,
                   l1.x + r1.x, l1.y + r1.y, l1.z + r1.z, l1.w + r1.w};
    float p[8];
    #pragma unroll
    for (int hd = 0; hd < 8; ++hd) {
        float t = xv[hd];
        t = t > 0.f ? t : NEG_SLOPE * t;
        p[hd] = __expf(t);
    }
    *(float4*)&pexp[(size_t)pos * NH] = make_float4(p[0], p[1], p[2], p[3]);
    *(float4*)&pexp[(size_t)pos * NH + 4] = make_float4(p[4], p[5], p[6], p[7]);
}

// ---- aggregate: one wave per node, lane = edge_group(3b) x head(3b) --------
__global__ __launch_bounds__(256) void agg_kernel(const unsigned short* __restrict__ h,
                                                  const int* __restrict__ row_ptr,
                                                  const int* __restrict__ csr_src,
                                                  const float* __restrict__ pexp,
                                                  const float* __restrict__ bias,
                                                  float* __restrict__ out) {
    int node = blockIdx.x * 4 + (threadIdx.x >> 6);
    if (node >= NN) return;
    int lane = threadIdx.x & 63;
    int eg = lane >> 3;        // edge slot within group of 8
    int fg = lane & 7;         // head (32 features)
    int beg = row_ptr[node];
    int end = row_ptr[node + 1];

    // sum of exp per head: coalesced pexp reads (addr = i0*8 + lane)
    float ssum = 0.f;
    for (int i0 = beg; i0 < end; i0 += 8) {
        int idx = i0 + eg;
        if (idx < end) ssum += pexp[(size_t)idx * NH + fg];
    }
    ssum += __shfl_xor(ssum, 8);
    ssum += __shfl_xor(ssum, 16);
    ssum += __shfl_xor(ssum, 32);
    float inv_s = (ssum > 0.f) ? 1.f / ssum : 0.f;

    // accumulate: 8 edges in flight, each lane owns 32 features of head fg
    float acc[32];
    #pragma unroll
    for (int j = 0; j < 32; ++j) acc[j] = 0.f;

    for (int i0 = beg; i0 < end; i0 += 8) {
        int idx = i0 + eg;
        if (idx < end) {
            int s = csr_src[idx];
            float a = pexp[(size_t)idx * NH + fg] * inv_s;
            const unsigned short* hp = h + (size_t)s * HF + fg * 32;
            #pragma unroll
            for (int c = 0; c < 4; ++c) {
                bf16x8 v = *(const bf16x8*)(hp + c * 8);
                #pragma unroll
                for (int k = 0; k < 8; ++k)
                    acc[c * 8 + k] = fmaf(bf2f((unsigned short)v[k]), a, acc[c * 8 + k]);
            }
        }
    }

    // recursive-halving reduce-scatter over eg (static reg indices only)
    int e2 = (lane >> 5) & 1, e1 = (lane >> 4) & 1, e0 = (lane >> 3) & 1;
    float t16[16];
    #pragma unroll
    for (int j = 0; j < 16; ++j) {
        float keep = e2 ? acc[16 + j] : acc[j];
        float send = e2 ? acc[j] : acc[16 + j];
        t16[j] = keep + __shfl_xor(send, 32);
    }
    float t8[8];
    #pragma unroll
    for (int j = 0; j < 8; ++j) {
        float keep = e1 ? t16[8 + j] : t16[j];
        float send = e1 ? t16[j] : t16[8 + j];
        t8[j] = keep + __shfl_xor(send, 16);
    }
    float t4[4];
    #pragma unroll
    for (int j = 0; j < 4; ++j) {
        float keep = e0 ? t8[4 + j] : t8[j];
        float send = e0 ? t8[j] : t8[4 + j];
        t4[j] = keep + __shfl_xor(send, 8);
    }

    int col = fg * 32 + eg * 4;
    float4 bv = *(const float4*)&bias[col];
    float4 o = make_float4(t4[0] + bv.x, t4[1] + bv.y, t4[2] + bv.z, t4[3] + bv.w);
    *(float4*)&out[(size_t)node * HF + col] = o;
}

extern "C" void kernel_launch(void* const* d_in, const int* in_sizes, int n_in,
                              void* d_out, int out_size, void* d_ws, size_t ws_size,
                              hipStream_t stream) {
    const float* feat = (const float*)d_in[0];
    const float* W    = (const float*)d_in[1];
    const float* al   = (const float*)d_in[2];
    const float* ar   = (const float*)d_in[3];
    const float* bias = (const float*)d_in[4];
    const int*   src  = (const int*)d_in[5];
    const int*   dst  = (const int*)d_in[6];
    float* out = (float*)d_out;

    char* ws = (char*)d_ws;
    size_t off = 0;
    unsigned short* h = (unsigned short*)(ws + off); off += (size_t)NN * HF * 2;     // 25.6 MB
    float* pexp = (float*)(ws + off);                off += (size_t)NE * NH * 4;     // 25.6 MB
    float* el = (float*)(ws + off);                  off += (size_t)NN * NH * 4;
    float* er = (float*)(ws + off);                  off += (size_t)NN * NH * 4;
    int* deg = (int*)(ws + off);                     off += (size_t)DEG_PAD * 4;
    int* row_ptr = (int*)(ws + off);                 off += (size_t)(NN + 1) * 4 + 60;
    off &= ~(size_t)63;
    int* cursor = (int*)(ws + off);                  off += (size_t)NN * 4;
    int* csr_src = (int*)(ws + off);                 off += (size_t)NE * 4;
    unsigned short* Wb_hi = (unsigned short*)(ws + off); off += (size_t)IN_F * HF * 2;
    unsigned short* Wb_lo = (unsigned short*)(ws + off); off += (size_t)IN_F * HF * 2;

    hipMemsetAsync(deg, 0, (size_t)DEG_PAD * 4, stream);

    wconv_kernel<<<256, 256, 0, stream>>>(W, Wb_hi, Wb_lo);
    gemm_kernel<<<(NN + 63) / 64, 256, 0, stream>>>(feat, Wb_hi, Wb_lo, h, NN);
    elr_kernel<<<NN / 4, 256, 0, stream>>>(h, al, ar, el, er);
    deg_kernel<<<NE / 256, 256, 0, stream>>>(dst, deg);
    scan_kernel<<<1, 1024, 0, stream>>>(deg, row_ptr, cursor);
    fill_kernel<<<NE / 256, 256, 0, stream>>>(src, dst, cursor, csr_src, el, er, pexp);
    agg_kernel<<<(NN + 3) / 4, 256, 0, stream>>>(h, row_ptr, csr_src, pexp, bias, out);
}

// Round 4
// 226.723 us; speedup vs baseline: 1.8824x; 1.0041x over previous
//
#include <hip/hip_runtime.h>
#include <math.h>

#define NN 50000
#define NE 800000
#define IN_F 256
#define HF 256   // H*F
#define NH 8
#define NEG_SLOPE 0.2f

#define DEG_PAD 57344   // 7 * 8192, scan processes 8192/iter unguarded

typedef short bf16x8 __attribute__((ext_vector_type(8)));
typedef float f32x16 __attribute__((ext_vector_type(16)));

__device__ __forceinline__ unsigned short f2bf(float x) {
    unsigned u = __float_as_uint(x);
    u += 0x7FFF + ((u >> 16) & 1);          // round-to-nearest-even
    return (unsigned short)(u >> 16);
}
__device__ __forceinline__ float bf2f(unsigned short b) {
    return __uint_as_float(((unsigned)b) << 16);
}

// ---- W -> transposed, K-step-blocked, chunk-swizzled bf16 (hi only) --------
__global__ __launch_bounds__(256) void wconv_kernel(const float* __restrict__ W,
                                                    unsigned short* __restrict__ Wb_hi) {
    int e = blockIdx.x * 256 + threadIdx.x;
    int k = e >> 8, n = e & 255;
    float x = W[e];
    int kt = k >> 5, kk = k & 31, c = kk >> 3, j = kk & 7;
    int slot = c ^ (n & 3);
    Wb_hi[((size_t)(kt * 256 + n)) * 32 + slot * 8 + j] = f2bf(x);
}

// ---- GEMM: h_bf16 = bf16(feat @ W), 2-term bf16-split MFMA -----------------
// (a_hi + a_lo) * b_hi : residual error a*b_lo ~ 2^-9 relative.
__global__ __launch_bounds__(256) void gemm_kernel(const float* __restrict__ feat,
                                                   const unsigned short* __restrict__ Wb_hi,
                                                   unsigned short* __restrict__ h, int M) {
    __shared__ __align__(16) unsigned short As_hi[64][32];
    __shared__ __align__(16) unsigned short As_lo[64][32];
    __shared__ __align__(16) unsigned short Bs_hi[256][32];

    const int tid = threadIdx.x;
    const int lane = tid & 63;
    const int wid = tid >> 6;
    const int bm = blockIdx.x * 64;

    f32x16 acc[2][2];
    #pragma unroll
    for (int mi = 0; mi < 2; ++mi)
        #pragma unroll
        for (int ni = 0; ni < 2; ++ni)
            #pragma unroll
            for (int r = 0; r < 16; ++r) acc[mi][ni][r] = 0.f;

    const int arow = tid >> 2;
    const int achk = tid & 3;
    const int aslot = achk ^ (arow & 3);
    const int grow = bm + arow;
    const float* aptr = feat + (size_t)grow * IN_F + achk * 8;

    for (int kt = 0; kt < 8; ++kt) {
        __syncthreads();
        float4 f0 = make_float4(0.f, 0.f, 0.f, 0.f), f1 = f0;
        if (grow < M) {
            f0 = *(const float4*)(aptr + kt * 32);
            f1 = *(const float4*)(aptr + kt * 32 + 4);
        }
        float xs[8] = {f0.x, f0.y, f0.z, f0.w, f1.x, f1.y, f1.z, f1.w};
        unsigned hi2[4], lo2[4];
        #pragma unroll
        for (int p = 0; p < 4; ++p) {
            unsigned short h0 = f2bf(xs[2 * p]), h1 = f2bf(xs[2 * p + 1]);
            unsigned short l0 = f2bf(xs[2 * p] - bf2f(h0));
            unsigned short l1 = f2bf(xs[2 * p + 1] - bf2f(h1));
            hi2[p] = (unsigned)h0 | ((unsigned)h1 << 16);
            lo2[p] = (unsigned)l0 | ((unsigned)l1 << 16);
        }
        *(int4*)&As_hi[arow][aslot * 8] = make_int4(hi2[0], hi2[1], hi2[2], hi2[3]);
        *(int4*)&As_lo[arow][aslot * 8] = make_int4(lo2[0], lo2[1], lo2[2], lo2[3]);
        {
            const int4* gh = (const int4*)(Wb_hi + (size_t)kt * 8192) + tid * 4;
            int4* dh = (int4*)&Bs_hi[tid][0];
            #pragma unroll
            for (int q = 0; q < 4; ++q) dh[q] = gh[q];
        }
        __syncthreads();
        #pragma unroll
        for (int ksc = 0; ksc < 2; ++ksc) {
            bf16x8 ah[2], av[2], bh[2];
            const int kc = ksc * 2 + (lane >> 5);
            #pragma unroll
            for (int mi = 0; mi < 2; ++mi) {
                int r = mi * 32 + (lane & 31);
                int slot = kc ^ (r & 3);
                ah[mi] = *(const bf16x8*)&As_hi[r][slot * 8];
                av[mi] = *(const bf16x8*)&As_lo[r][slot * 8];
            }
            #pragma unroll
            for (int ni = 0; ni < 2; ++ni) {
                int n = wid * 64 + ni * 32 + (lane & 31);
                int slot = kc ^ (n & 3);
                bh[ni] = *(const bf16x8*)&Bs_hi[n][slot * 8];
            }
            #pragma unroll
            for (int mi = 0; mi < 2; ++mi)
                #pragma unroll
                for (int ni = 0; ni < 2; ++ni) {
                    acc[mi][ni] = __builtin_amdgcn_mfma_f32_32x32x16_bf16(ah[mi], bh[ni], acc[mi][ni], 0, 0, 0);
                    acc[mi][ni] = __builtin_amdgcn_mfma_f32_32x32x16_bf16(av[mi], bh[ni], acc[mi][ni], 0, 0, 0);
                }
        }
    }
    #pragma unroll
    for (int mi = 0; mi < 2; ++mi)
        #pragma unroll
        for (int ni = 0; ni < 2; ++ni)
            #pragma unroll
            for (int r = 0; r < 16; ++r) {
                int row = mi * 32 + (r & 3) + 8 * (r >> 2) + 4 * (lane >> 5);
                int col = wid * 64 + ni * 32 + (lane & 31);
                int gr = bm + row;
                if (gr < M) h[(size_t)gr * HF + col] = f2bf(acc[mi][ni][r]);
            }
}

// ---- el/er per node --------------------------------------------------------
__global__ __launch_bounds__(256) void elr_kernel(const unsigned short* __restrict__ h,
                                                  const float* __restrict__ al,
                                                  const float* __restrict__ ar,
                                                  float* __restrict__ el,
                                                  float* __restrict__ er) {
    int node = blockIdx.x * 4 + (threadIdx.x >> 6);
    if (node >= NN) return;
    int lane = threadIdx.x & 63;
    short4 hv = *(const short4*)&h[(size_t)node * HF + lane * 4];
    float h0 = bf2f((unsigned short)hv.x), h1 = bf2f((unsigned short)hv.y);
    float h2 = bf2f((unsigned short)hv.z), h3 = bf2f((unsigned short)hv.w);
    float4 alv = *(const float4*)&al[lane * 4];
    float4 arv = *(const float4*)&ar[lane * 4];
    float pl = h0 * alv.x + h1 * alv.y + h2 * alv.z + h3 * alv.w;
    float pr = h0 * arv.x + h1 * arv.y + h2 * arv.z + h3 * arv.w;
    #pragma unroll
    for (int off = 1; off < 8; off <<= 1) {
        pl += __shfl_xor(pl, off);
        pr += __shfl_xor(pr, off);
    }
    if ((lane & 7) == 0) {
        el[node * NH + (lane >> 3)] = pl;
        er[node * NH + (lane >> 3)] = pr;
    }
}

// ---- CSR build -------------------------------------------------------------
__global__ void deg_kernel(const int* __restrict__ dst, int* __restrict__ deg) {
    int e = blockIdx.x * 256 + threadIdx.x;
    if (e < NE) atomicAdd(&deg[dst[e]], 1);
}

__global__ __launch_bounds__(1024) void scan_kernel(const int* __restrict__ deg,
                                                    int* __restrict__ row_ptr,
                                                    int* __restrict__ cursor) {
    __shared__ int wsum[16];
    int tid = threadIdx.x, lane = tid & 63, wid = tid >> 6;
    int carry = 0;
    if (tid == 0) row_ptr[0] = 0;
    for (int base = 0; base < DEG_PAD; base += 8192) {
        int i0 = base + tid * 8;
        int4 a = *(const int4*)&deg[i0];
        int4 b = *(const int4*)&deg[i0 + 4];
        int v[8] = {a.x, a.y, a.z, a.w, b.x, b.y, b.z, b.w};
        int s8 = 0;
        #pragma unroll
        for (int j = 0; j < 8; ++j) s8 += v[j];
        int x = s8;
        #pragma unroll
        for (int off = 1; off < 64; off <<= 1) {
            int y = __shfl_up(x, off);
            if (lane >= off) x += y;
        }
        if (lane == 63) wsum[wid] = x;
        __syncthreads();
        int wadd = 0, tot = 0;
        #pragma unroll
        for (int w = 0; w < 16; ++w) {
            int s = wsum[w];
            tot += s;
            if (w < wid) wadd += s;
        }
        int r = carry + wadd + (x - s8);
        #pragma unroll
        for (int j = 0; j < 8; ++j) {
            int i = i0 + j;
            if (i < NN) { cursor[i] = r; row_ptr[i + 1] = r + v[j]; }
            r += v[j];
        }
        carry += tot;
        __syncthreads();
    }
}

__global__ void fill_kernel(const int* __restrict__ src, const int* __restrict__ dst,
                            int* __restrict__ cursor, int* __restrict__ csr_src) {
    int e = blockIdx.x * 256 + threadIdx.x;
    if (e < NE) {
        int pos = atomicAdd(&cursor[dst[e]], 1);
        csr_src[pos] = src[e];
    }
}

// ---- single-pass aggregate: lane = edge_slot(3b) x head(3b), 16 edges/iter -
__global__ __launch_bounds__(256) void agg_kernel(const unsigned short* __restrict__ h,
                                                  const float* __restrict__ el,
                                                  const float* __restrict__ er,
                                                  const int* __restrict__ row_ptr,
                                                  const int* __restrict__ csr_src,
                                                  const float* __restrict__ bias,
                                                  float* __restrict__ out) {
    int node = blockIdx.x * 4 + (threadIdx.x >> 6);
    if (node >= NN) return;
    int lane = threadIdx.x & 63;
    int eg = lane >> 3;        // edge slot
    int fg = lane & 7;         // head (32 features)
    int beg = row_ptr[node];
    int end = row_ptr[node + 1];
    float er_mine = er[(size_t)node * NH + fg];

    float ssum = 0.f;
    float acc[32];
    #pragma unroll
    for (int j = 0; j < 32; ++j) acc[j] = 0.f;

    for (int i0 = beg; i0 < end; i0 += 16) {
        int idxA = i0 + eg;
        int idxB = i0 + 8 + eg;
        bool vA = idxA < end, vB = idxB < end;
        int sA = csr_src[vA ? idxA : beg];
        int sB = csr_src[vB ? idxB : beg];
        float eA = el[(size_t)sA * NH + fg] + er_mine;
        float eB = el[(size_t)sB * NH + fg] + er_mine;
        eA = eA > 0.f ? eA : NEG_SLOPE * eA;
        eB = eB > 0.f ? eB : NEG_SLOPE * eB;
        float pA = vA ? __expf(eA) : 0.f;
        float pB = vB ? __expf(eB) : 0.f;
        ssum += pA + pB;
        const unsigned short* hpA = h + (size_t)sA * HF + fg * 32;
        const unsigned short* hpB = h + (size_t)sB * HF + fg * 32;
        bf16x8 va[4], vb[4];
        #pragma unroll
        for (int c = 0; c < 4; ++c) { va[c] = *(const bf16x8*)(hpA + c * 8); }
        #pragma unroll
        for (int c = 0; c < 4; ++c) { vb[c] = *(const bf16x8*)(hpB + c * 8); }
        #pragma unroll
        for (int c = 0; c < 4; ++c)
            #pragma unroll
            for (int k = 0; k < 8; ++k) {
                acc[c * 8 + k] = fmaf(bf2f((unsigned short)va[c][k]), pA, acc[c * 8 + k]);
                acc[c * 8 + k] = fmaf(bf2f((unsigned short)vb[c][k]), pB, acc[c * 8 + k]);
            }
    }

    // reduce ssum over edge slots (keep head bits)
    ssum += __shfl_xor(ssum, 8);
    ssum += __shfl_xor(ssum, 16);
    ssum += __shfl_xor(ssum, 32);
    float inv_s = (ssum > 0.f) ? 1.f / ssum : 0.f;

    // recursive-halving reduce-scatter over eg (static reg indices only)
    int e2 = (lane >> 5) & 1, e1 = (lane >> 4) & 1, e0 = (lane >> 3) & 1;
    float t16[16];
    #pragma unroll
    for (int j = 0; j < 16; ++j) {
        float keep = e2 ? acc[16 + j] : acc[j];
        float send = e2 ? acc[j] : acc[16 + j];
        t16[j] = keep + __shfl_xor(send, 32);
    }
    float t8[8];
    #pragma unroll
    for (int j = 0; j < 8; ++j) {
        float keep = e1 ? t16[8 + j] : t16[j];
        float send = e1 ? t16[j] : t16[8 + j];
        t8[j] = keep + __shfl_xor(send, 16);
    }
    float t4[4];
    #pragma unroll
    for (int j = 0; j < 4; ++j) {
        float keep = e0 ? t8[4 + j] : t8[j];
        float send = e0 ? t8[j] : t8[4 + j];
        t4[j] = keep + __shfl_xor(send, 8);
    }

    int col = fg * 32 + eg * 4;
    float4 bv = *(const float4*)&bias[col];
    float4 o = make_float4(fmaf(t4[0], inv_s, bv.x), fmaf(t4[1], inv_s, bv.y),
                           fmaf(t4[2], inv_s, bv.z), fmaf(t4[3], inv_s, bv.w));
    *(float4*)&out[(size_t)node * HF + col] = o;
}

extern "C" void kernel_launch(void* const* d_in, const int* in_sizes, int n_in,
                              void* d_out, int out_size, void* d_ws, size_t ws_size,
                              hipStream_t stream) {
    const float* feat = (const float*)d_in[0];
    const float* W    = (const float*)d_in[1];
    const float* al   = (const float*)d_in[2];
    const float* ar   = (const float*)d_in[3];
    const float* bias = (const float*)d_in[4];
    const int*   src  = (const int*)d_in[5];
    const int*   dst  = (const int*)d_in[6];
    float* out = (float*)d_out;

    char* ws = (char*)d_ws;
    size_t off = 0;
    unsigned short* h = (unsigned short*)(ws + off); off += (size_t)NN * HF * 2;     // 25.6 MB
    float* el = (float*)(ws + off);                  off += (size_t)NN * NH * 4;
    float* er = (float*)(ws + off);                  off += (size_t)NN * NH * 4;
    int* deg = (int*)(ws + off);                     off += (size_t)DEG_PAD * 4;
    int* row_ptr = (int*)(ws + off);                 off += (size_t)(NN + 1) * 4 + 60;
    off &= ~(size_t)63;
    int* cursor = (int*)(ws + off);                  off += (size_t)NN * 4;
    int* csr_src = (int*)(ws + off);                 off += (size_t)NE * 4;
    unsigned short* Wb_hi = (unsigned short*)(ws + off); off += (size_t)IN_F * HF * 2;

    hipMemsetAsync(deg, 0, (size_t)DEG_PAD * 4, stream);

    wconv_kernel<<<256, 256, 0, stream>>>(W, Wb_hi);
    gemm_kernel<<<(NN + 63) / 64, 256, 0, stream>>>(feat, Wb_hi, h, NN);
    elr_kernel<<<NN / 4, 256, 0, stream>>>(h, al, ar, el, er);
    deg_kernel<<<NE / 256, 256, 0, stream>>>(dst, deg);
    scan_kernel<<<1, 1024, 0, stream>>>(deg, row_ptr, cursor);
    fill_kernel<<<NE / 256, 256, 0, stream>>>(src, dst, cursor, csr_src);
    agg_kernel<<<(NN + 3) / 4, 256, 0, stream>>>(h, el, er, row_ptr, csr_src, bias, out);
}